// Round 4
// baseline (190.190 us; speedup 1.0000x reference)
//
#include <hip/hip_runtime.h>

// z(8,128,64,64) f32, codes(16,256,8) f32
// out: soft(8,64,64,128) | hard(8,64,64,128) | idx(8,64,64,16) as f32
#define NPOS 32768
#define CCH  128
#define LL   16
#define KK   256
#define CD   8

typedef float f32x2  __attribute__((ext_vector_type(2)));
typedef float f32x4  __attribute__((ext_vector_type(4)));
typedef float f32x16 __attribute__((ext_vector_type(16)));

#if __has_builtin(__builtin_amdgcn_exp2f)
#define EXP2NEG(x) __builtin_amdgcn_exp2f(-(x))
#else
#define EXP2NEG(x) __expf(-0.6931471805599453f * (x))
#endif

// F = sqrt(2)*log2(e): with hv' = F*hv, c' = F*c,
//   dot = -0.5*|hv'|^2 - 0.5*|c'|^2 + hv'.c' = -(log2e * dist)^2
//   => exp2(-sqrt(-dot)) == exp(-dist)  (softmin temperature exactly 1.0)
#define FS    2.0402788939f
#define INVFS 0.4901290717f   // ln2/sqrt(2) == 1/FS exactly

// ws (floats): [0,32768) scaled codes [16][256][8] ; [32768,36864) seeds -0.5|c'|^2 [16][256]
#define WS_SEED_OFF 32768

__global__ __launch_bounds__(256) void prep_codes(
    const float* __restrict__ codes, float* __restrict__ ws)
{
    const int t = (int)(blockIdx.x * 256 + threadIdx.x);   // 4096 = 16*256
    const int l = t >> 8, k = t & 255;
    const float* g = codes + ((size_t)(l * KK + k)) * CD;
    f32x4 q0 = FS * ((const f32x4*)g)[0];
    f32x4 q1 = FS * ((const f32x4*)g)[1];
    f32x4* d = (f32x4*)(ws + (size_t)l * 2048 + (size_t)k * CD);
    d[0] = q0;
    d[1] = q1;
    float c2 = q0[0]*q0[0] + q0[1]*q0[1] + q0[2]*q0[2] + q0[3]*q0[3]
             + q1[0]*q1[0] + q1[1]*q1[1] + q1[2]*q1[2] + q1[3]*q1[3];
    ws[WS_SEED_OFF + l * KK + k] = -0.5f * c2;
}

__global__ __launch_bounds__(256) void soft_hard_enc(
    const float* __restrict__ z, const float* __restrict__ codes,
    const float* __restrict__ ws, float* __restrict__ out)
{
    const int tid = (int)threadIdx.x;
    const int bid = (int)blockIdx.x;
    const int lBase   = (bid & 3) * 4;        // 4 latents per block (write-line locality)
    const int posBase = (bid >> 2) * 128;     // 128 positions per block
    const int lgrp = tid >> 6;                // wave index = latent offset (wave-uniform)
    const int l4   = lBase + lgrp;
    const int pA   = posBase + (tid & 63);    // 2 positions per thread
    const int pB   = pA + 64;
    const int b    = pA >> 12;                // same image for pA and pB
    const int whA  = pA & 4095;

    // hv loads (coalesced per channel), scaled; -0.5*|hv'|^2
    const float* zp = z + (((size_t)(b * CCH + l4 * CD)) << 12) + whA;
    float hvA[CD], hvB[CD];
    float hv2A = 0.f, hv2B = 0.f;
#pragma unroll
    for (int c = 0; c < CD; ++c) {
        float va = FS * zp[((size_t)c) << 12];
        float vb = FS * zp[(((size_t)c) << 12) + 64];
        hvA[c] = va; hvB[c] = vb;
        hv2A = __builtin_fmaf(va, va, hv2A);
        hv2B = __builtin_fmaf(vb, vb, hv2B);
    }
    hv2A *= -0.5f;
    hv2B *= -0.5f;

    // wave-uniform code streams -> s_load into SGPRs; SGPR feeds v_fma src directly
    const f32x16* cc = (const f32x16*)(ws + (size_t)l4 * 2048);           // [128] pairs
    const f32x2*  cs = (const f32x2*)(ws + WS_SEED_OFF + (size_t)l4 * KK); // [128] seed pairs

    float accA[CD], accB[CD];
#pragma unroll
    for (int c = 0; c < CD; ++c) { accA[c] = 0.f; accB[c] = 0.f; }
    float ssA = 0.f, ssB = 0.f;
    float bdAe = -3.4e38f, bdAo = -3.4e38f, bdBe = -3.4e38f, bdBo = -3.4e38f;
    int   bjAe = 0, bjAo = 0, bjBe = 0, bjBo = 0;

    // ring-of-4 scalar prefetch (no rotation movs; ~3-body issue-to-use distance)
    f32x16 C0 = cc[0], C1 = cc[1], C2 = cc[2], C3 = cc[3];
    f32x2  S0 = cs[0], S1 = cs[1], S2 = cs[2], S3 = cs[3];

#define BODY(CU, SU, J)                                                        \
    {                                                                          \
        const int jj = (J);                                                    \
        float dAe = SU[0] + hv2A, dAo = SU[1] + hv2A;                          \
        float dBe = SU[0] + hv2B, dBo = SU[1] + hv2B;                          \
        _Pragma("unroll")                                                      \
        for (int c = 0; c < CD; ++c) {                                         \
            dAe = __builtin_fmaf(CU[c],      hvA[c], dAe);                     \
            dAo = __builtin_fmaf(CU[CD + c], hvA[c], dAo);                     \
            dBe = __builtin_fmaf(CU[c],      hvB[c], dBe);                     \
            dBo = __builtin_fmaf(CU[CD + c], hvB[c], dBo);                     \
        }                                                                      \
        float eAe = EXP2NEG(__builtin_amdgcn_sqrtf(-dAe));                     \
        float eAo = EXP2NEG(__builtin_amdgcn_sqrtf(-dAo));                     \
        float eBe = EXP2NEG(__builtin_amdgcn_sqrtf(-dBe));                     \
        float eBo = EXP2NEG(__builtin_amdgcn_sqrtf(-dBo));                     \
        ssA += eAe; ssA += eAo; ssB += eBe; ssB += eBo;                        \
        _Pragma("unroll")                                                      \
        for (int c = 0; c < CD; ++c) {                                         \
            accA[c] = __builtin_fmaf(CU[c],      eAe, accA[c]);                \
            accA[c] = __builtin_fmaf(CU[CD + c], eAo, accA[c]);                \
            accB[c] = __builtin_fmaf(CU[c],      eBe, accB[c]);                \
            accB[c] = __builtin_fmaf(CU[CD + c], eBo, accB[c]);                \
        }                                                                      \
        if (dAe > bdAe) bjAe = jj;                                             \
        bdAe = fmaxf(bdAe, dAe);                                               \
        if (dAo > bdAo) bjAo = jj;                                             \
        bdAo = fmaxf(bdAo, dAo);                                               \
        if (dBe > bdBe) bjBe = jj;                                             \
        bdBe = fmaxf(bdBe, dBe);                                               \
        if (dBo > bdBo) bjBo = jj;                                             \
        bdBo = fmaxf(bdBo, dBo);                                               \
        CU = cc[(jj + 4) & 127];                                               \
        SU = cs[(jj + 4) & 127];                                               \
    }

    for (int j = 0; j < KK / 2; j += 4) {
        BODY(C0, S0, j)
        BODY(C1, S1, j + 1)
        BODY(C2, S2, j + 2)
        BODY(C3, S3, j + 3)
    }
#undef BODY

    // merge parities per position; exact-tie -> smaller k (first occurrence)
    int keA = 2 * bjAe, koA = 2 * bjAo + 1;
    int bestA = keA;
    if (bdAo > bdAe || (bdAo == bdAe && koA < keA)) bestA = koA;
    int keB = 2 * bjBe, koB = 2 * bjBo + 1;
    int bestB = keB;
    if (bdBo > bdBe || (bdBo == bdBe && koB < keB)) bestB = koB;

    const float scA = INVFS / ssA;   // un-scale codes + softmax normalize
    const float scB = INVFS / ssB;

    const size_t obaseA = (size_t)pA * CCH + (size_t)(l4 * CD);
    const size_t obaseB = (size_t)pB * CCH + (size_t)(l4 * CD);
    *(f32x4*)&out[obaseA]     = (f32x4){accA[0]*scA, accA[1]*scA, accA[2]*scA, accA[3]*scA};
    *(f32x4*)&out[obaseA + 4] = (f32x4){accA[4]*scA, accA[5]*scA, accA[6]*scA, accA[7]*scA};
    *(f32x4*)&out[obaseB]     = (f32x4){accB[0]*scB, accB[1]*scB, accB[2]*scB, accB[3]*scB};
    *(f32x4*)&out[obaseB + 4] = (f32x4){accB[4]*scB, accB[5]*scB, accB[6]*scB, accB[7]*scB};

    // hard: gather un-scaled code from global (L2-hot 128 KB)
    float* outh = out + (size_t)NPOS * CCH;
    {
        const float* hp = codes + ((size_t)(l4 * KK + bestA)) * CD;
        *(f32x4*)&outh[obaseA]     = ((const f32x4*)hp)[0];
        *(f32x4*)&outh[obaseA + 4] = ((const f32x4*)hp)[1];
    }
    {
        const float* hp = codes + ((size_t)(l4 * KK + bestB)) * CD;
        *(f32x4*)&outh[obaseB]     = ((const f32x4*)hp)[0];
        *(f32x4*)&outh[obaseB + 4] = ((const f32x4*)hp)[1];
    }

    float* outi = out + (size_t)2 * NPOS * CCH;
    outi[(size_t)pA * LL + l4] = (float)bestA;
    outi[(size_t)pB * LL + l4] = (float)bestB;
}

extern "C" void kernel_launch(void* const* d_in, const int* in_sizes, int n_in,
                              void* d_out, int out_size, void* d_ws, size_t ws_size,
                              hipStream_t stream) {
    const float* z     = (const float*)d_in[0];
    const float* codes = (const float*)d_in[1];
    float* ws  = (float*)d_ws;
    float* out = (float*)d_out;
    prep_codes<<<dim3(16), dim3(256), 0, stream>>>(codes, ws);
    soft_hard_enc<<<dim3((NPOS / 128) * 4), dim3(256), 0, stream>>>(z, codes, ws, out);
}

// Round 5
// 145.513 us; speedup vs baseline: 1.3070x; 1.3070x over previous
//
#include <hip/hip_runtime.h>

// z(8,128,64,64) f32, codes(16,256,8) f32
// out: soft(8,64,64,128) | hard(8,64,64,128) | idx(8,64,64,16) as f32
#define NPOS 32768
#define CCH  128
#define LL   16
#define KK   256
#define CD   8

typedef float f32x2  __attribute__((ext_vector_type(2)));
typedef float f32x4  __attribute__((ext_vector_type(4)));
typedef float f32x16 __attribute__((ext_vector_type(16)));

#if __has_builtin(__builtin_amdgcn_exp2f)
#define EXP2NEG(x) __builtin_amdgcn_exp2f(-(x))
#else
#define EXP2NEG(x) __expf(-0.6931471805599453f * (x))
#endif

// F = sqrt(2)*log2(e): with hv' = F*hv, c' = F*c,
//   dot = -0.5*|hv'|^2 - 0.5*|c'|^2 + hv'.c' = -(log2e * dist)^2
//   => exp2(-sqrt(-dot)) == exp(-dist)  (softmin temperature exactly 1.0)
#define FS    2.0402788939f
#define INVFS 0.4901290717f   // ln2/sqrt(2) == 1/FS exactly

// ws (floats): [0,32768) scaled codes [16][256][8] ; [32768,36864) seeds -0.5|c'|^2 [16][256]
#define WS_SEED_OFF 32768

__global__ __launch_bounds__(256) void prep_codes(
    const float* __restrict__ codes, float* __restrict__ ws)
{
    const int t = (int)(blockIdx.x * 256 + threadIdx.x);   // 4096 = 16*256
    const int l = t >> 8, k = t & 255;
    const float* g = codes + ((size_t)(l * KK + k)) * CD;
    f32x4 q0 = FS * ((const f32x4*)g)[0];
    f32x4 q1 = FS * ((const f32x4*)g)[1];
    f32x4* d = (f32x4*)(ws + (size_t)l * 2048 + (size_t)k * CD);
    d[0] = q0;
    d[1] = q1;
    float c2 = q0[0]*q0[0] + q0[1]*q0[1] + q0[2]*q0[2] + q0[3]*q0[3]
             + q1[0]*q1[0] + q1[1]*q1[1] + q1[2]*q1[2] + q1[3]*q1[3];
    ws[WS_SEED_OFF + l * KK + k] = -0.5f * c2;
}

__global__ __launch_bounds__(256) void soft_hard_enc(
    const float* __restrict__ z, const float* __restrict__ codes,
    const float* __restrict__ ws, float* __restrict__ out)
{
    const int tid = (int)threadIdx.x;
    const int bid = (int)blockIdx.x;
    // XCD-aware decomposition: all 16 latent-blocks of one pos-chunk share an XCD
    // (bids congruent mod 8 -> same XCD under round-robin dispatch), so their
    // 32B partial-line writes merge in that XCD's L2 -> full-line HBM writes.
    const int xcd   = bid & 7;
    const int m     = bid >> 3;           // [0,128)
    const int l4    = m & 15;             // BLOCK-uniform latent -> s_load streams
    const int grp   = m >> 4;             // [0,8)
    const int chunk = grp * 8 + xcd;      // [0,64) : 512 positions each
    const int posBase = chunk * 512;
    const int pA  = posBase + tid;        // 2 positions per thread
    const int pB  = pA + 256;
    const int b   = pA >> 12;             // 512 | 4096 -> same image for pA,pB
    const int whA = pA & 4095;

    // hv loads (coalesced per channel), scaled; -0.5*|hv'|^2
    const float* zp = z + (((size_t)(b * CCH + l4 * CD)) << 12) + whA;
    float hvA[CD], hvB[CD];
    float hv2A = 0.f, hv2B = 0.f;
#pragma unroll
    for (int c = 0; c < CD; ++c) {
        float va = FS * zp[((size_t)c) << 12];
        float vb = FS * zp[(((size_t)c) << 12) + 256];
        hvA[c] = va; hvB[c] = vb;
        hv2A = __builtin_fmaf(va, va, hv2A);
        hv2B = __builtin_fmaf(vb, vb, hv2B);
    }
    hv2A *= -0.5f;
    hv2B *= -0.5f;

    // block-uniform code streams -> s_load into SGPRs; SGPR feeds v_fma src directly
    const f32x16* cc = (const f32x16*)(ws + (size_t)l4 * 2048);            // [128] pairs
    const f32x2*  cs = (const f32x2*)(ws + WS_SEED_OFF + (size_t)l4 * KK); // [128] seed pairs

    float accA[CD], accB[CD];
#pragma unroll
    for (int c = 0; c < CD; ++c) { accA[c] = 0.f; accB[c] = 0.f; }
    float ssA = 0.f, ssB = 0.f;
    float bdAe = -3.4e38f, bdAo = -3.4e38f, bdBe = -3.4e38f, bdBo = -3.4e38f;
    int   bjAe = 0, bjAo = 0, bjBe = 0, bjBo = 0;

    // ring-of-4 scalar prefetch (no rotation movs; ~3-body issue-to-use distance)
    f32x16 C0 = cc[0], C1 = cc[1], C2 = cc[2], C3 = cc[3];
    f32x2  S0 = cs[0], S1 = cs[1], S2 = cs[2], S3 = cs[3];

#define BODY(CU, SU, J)                                                        \
    {                                                                          \
        const int jj = (J);                                                    \
        float dAe = SU[0] + hv2A, dAo = SU[1] + hv2A;                          \
        float dBe = SU[0] + hv2B, dBo = SU[1] + hv2B;                          \
        _Pragma("unroll")                                                      \
        for (int c = 0; c < CD; ++c) {                                         \
            dAe = __builtin_fmaf(CU[c],      hvA[c], dAe);                     \
            dAo = __builtin_fmaf(CU[CD + c], hvA[c], dAo);                     \
            dBe = __builtin_fmaf(CU[c],      hvB[c], dBe);                     \
            dBo = __builtin_fmaf(CU[CD + c], hvB[c], dBo);                     \
        }                                                                      \
        float eAe = EXP2NEG(__builtin_amdgcn_sqrtf(-dAe));                     \
        float eAo = EXP2NEG(__builtin_amdgcn_sqrtf(-dAo));                     \
        float eBe = EXP2NEG(__builtin_amdgcn_sqrtf(-dBe));                     \
        float eBo = EXP2NEG(__builtin_amdgcn_sqrtf(-dBo));                     \
        ssA += eAe; ssA += eAo; ssB += eBe; ssB += eBo;                        \
        _Pragma("unroll")                                                      \
        for (int c = 0; c < CD; ++c) {                                         \
            accA[c] = __builtin_fmaf(CU[c],      eAe, accA[c]);                \
            accA[c] = __builtin_fmaf(CU[CD + c], eAo, accA[c]);                \
            accB[c] = __builtin_fmaf(CU[c],      eBe, accB[c]);                \
            accB[c] = __builtin_fmaf(CU[CD + c], eBo, accB[c]);                \
        }                                                                      \
        if (dAe > bdAe) bjAe = jj;                                             \
        bdAe = fmaxf(bdAe, dAe);                                               \
        if (dAo > bdAo) bjAo = jj;                                             \
        bdAo = fmaxf(bdAo, dAo);                                               \
        if (dBe > bdBe) bjBe = jj;                                             \
        bdBe = fmaxf(bdBe, dBe);                                               \
        if (dBo > bdBo) bjBo = jj;                                             \
        bdBo = fmaxf(bdBo, dBo);                                               \
        CU = cc[(jj + 4) & 127];                                               \
        SU = cs[(jj + 4) & 127];                                               \
    }

    for (int j = 0; j < KK / 2; j += 4) {
        BODY(C0, S0, j)
        BODY(C1, S1, j + 1)
        BODY(C2, S2, j + 2)
        BODY(C3, S3, j + 3)
    }
#undef BODY

    // merge parities per position; exact-tie -> smaller k (first occurrence)
    int keA = 2 * bjAe, koA = 2 * bjAo + 1;
    int bestA = keA;
    if (bdAo > bdAe || (bdAo == bdAe && koA < keA)) bestA = koA;
    int keB = 2 * bjBe, koB = 2 * bjBo + 1;
    int bestB = keB;
    if (bdBo > bdBe || (bdBo == bdBe && koB < keB)) bestB = koB;

    const float scA = INVFS / ssA;   // un-scale codes + softmax normalize
    const float scB = INVFS / ssB;

    const size_t obaseA = (size_t)pA * CCH + (size_t)(l4 * CD);
    const size_t obaseB = (size_t)pB * CCH + (size_t)(l4 * CD);
    *(f32x4*)&out[obaseA]     = (f32x4){accA[0]*scA, accA[1]*scA, accA[2]*scA, accA[3]*scA};
    *(f32x4*)&out[obaseA + 4] = (f32x4){accA[4]*scA, accA[5]*scA, accA[6]*scA, accA[7]*scA};
    *(f32x4*)&out[obaseB]     = (f32x4){accB[0]*scB, accB[1]*scB, accB[2]*scB, accB[3]*scB};
    *(f32x4*)&out[obaseB + 4] = (f32x4){accB[4]*scB, accB[5]*scB, accB[6]*scB, accB[7]*scB};

    // hard: gather un-scaled code from global (L2-hot 128 KB)
    float* outh = out + (size_t)NPOS * CCH;
    {
        const float* hp = codes + ((size_t)(l4 * KK + bestA)) * CD;
        *(f32x4*)&outh[obaseA]     = ((const f32x4*)hp)[0];
        *(f32x4*)&outh[obaseA + 4] = ((const f32x4*)hp)[1];
    }
    {
        const float* hp = codes + ((size_t)(l4 * KK + bestB)) * CD;
        *(f32x4*)&outh[obaseB]     = ((const f32x4*)hp)[0];
        *(f32x4*)&outh[obaseB + 4] = ((const f32x4*)hp)[1];
    }

    float* outi = out + (size_t)2 * NPOS * CCH;
    outi[(size_t)pA * LL + l4] = (float)bestA;
    outi[(size_t)pB * LL + l4] = (float)bestB;
}

extern "C" void kernel_launch(void* const* d_in, const int* in_sizes, int n_in,
                              void* d_out, int out_size, void* d_ws, size_t ws_size,
                              hipStream_t stream) {
    const float* z     = (const float*)d_in[0];
    const float* codes = (const float*)d_in[1];
    float* ws  = (float*)d_ws;
    float* out = (float*)d_out;
    prep_codes<<<dim3(16), dim3(256), 0, stream>>>(codes, ws);
    soft_hard_enc<<<dim3((NPOS / 512) * LL), dim3(256), 0, stream>>>(z, codes, ws, out);
}

// Round 6
// 145.342 us; speedup vs baseline: 1.3086x; 1.0012x over previous
//
#include <hip/hip_runtime.h>

// z(8,128,64,64) f32, codes(16,256,8) f32
// out: soft(8,64,64,128) | hard(8,64,64,128) | idx(8,64,64,16) as f32
#define NPOS 32768
#define CCH  128
#define LL   16
#define KK   256
#define CD   8

typedef float f32x2  __attribute__((ext_vector_type(2)));
typedef float f32x4  __attribute__((ext_vector_type(4)));
typedef float f32x8  __attribute__((ext_vector_type(8)));

#if __has_builtin(__builtin_amdgcn_exp2f)
#define EXP2NEG(x) __builtin_amdgcn_exp2f(-(x))
#else
#define EXP2NEG(x) __expf(-0.6931471805599453f * (x))
#endif

// F = sqrt(2)*log2(e): with hv' = F*hv, c' = F*c,
//   dot = -0.5*|hv'|^2 - 0.5*|c'|^2 + hv'.c' = -(log2e * dist)^2
//   => exp2(-sqrt(-dot)) == exp(-dist)  (softmin temperature exactly 1.0)
#define FS    2.0402788939f
#define INVFS 0.4901290717f   // ln2/sqrt(2) == 1/FS exactly

// ws (floats): [0,32768) scaled codes [16][256][8] ; [32768,36864) seeds -0.5|c'|^2 [16][256]
#define WS_SEED_OFF 32768

__global__ __launch_bounds__(256) void prep_codes(
    const float* __restrict__ codes, float* __restrict__ ws)
{
    const int t = (int)(blockIdx.x * 256 + threadIdx.x);   // 4096 = 16*256
    const int l = t >> 8, k = t & 255;
    const float* g = codes + ((size_t)(l * KK + k)) * CD;
    f32x4 q0 = FS * ((const f32x4*)g)[0];
    f32x4 q1 = FS * ((const f32x4*)g)[1];
    f32x4* d = (f32x4*)(ws + (size_t)l * 2048 + (size_t)k * CD);
    d[0] = q0;
    d[1] = q1;
    float c2 = q0[0]*q0[0] + q0[1]*q0[1] + q0[2]*q0[2] + q0[3]*q0[3]
             + q1[0]*q1[0] + q1[1]*q1[1] + q1[2]*q1[2] + q1[3]*q1[3];
    ws[WS_SEED_OFF + l * KK + k] = -0.5f * c2;
}

__global__ __launch_bounds__(256) void soft_hard_enc(
    const float* __restrict__ z, const float* __restrict__ codes,
    const float* __restrict__ ws, float* __restrict__ out)
{
    const int tid = (int)threadIdx.x;
    const int bid = (int)blockIdx.x;
    // XCD-aware decomposition (kept from R5): latent is BLOCK-uniform.
    const int xcd   = bid & 7;
    const int m     = bid >> 3;           // [0,128)
    const int l4    = m & 15;             // block-uniform latent
    const int grp   = m >> 4;             // [0,8)
    const int chunk = grp * 8 + xcd;      // [0,64) : 512 positions each
    const int posBase = chunk * 512;
    const int pA  = posBase + tid;        // 2 positions per thread
    const int pB  = pA + 256;
    const int b   = pA >> 12;
    const int whA = pA & 4095;

    // hv loads (coalesced per channel), scaled; -0.5*|hv'|^2
    const float* zp = z + (((size_t)(b * CCH + l4 * CD)) << 12) + whA;
    float hvA[CD], hvB[CD];
    float hv2A = 0.f, hv2B = 0.f;
#pragma unroll
    for (int c = 0; c < CD; ++c) {
        float va = FS * zp[((size_t)c) << 12];
        float vb = FS * zp[(((size_t)c) << 12) + 256];
        hvA[c] = va; hvB[c] = vb;
        hv2A = __builtin_fmaf(va, va, hv2A);
        hv2B = __builtin_fmaf(vb, vb, hv2B);
    }
    hv2A *= -0.5f;
    hv2B *= -0.5f;

    // Code stream: wave-uniform-address GLOBAL loads into VGPRs.
    // vmcnt is in-order & partially waitable -> compiler software-pipelines
    // robustly (unlike SMEM, whose out-of-order retire forces lgkmcnt(0)
    // full drains that defeated the R5 SGPR ring). 9 KB/block -> L1-resident.
    const f32x8* cc  = (const f32x8*)(ws + (size_t)l4 * 2048);          // [256] codes
    const f32x4* cs4 = (const f32x4*)(ws + WS_SEED_OFF + (size_t)l4 * KK); // [64] seed quads

    float accA[CD], accB[CD];
#pragma unroll
    for (int c = 0; c < CD; ++c) { accA[c] = 0.f; accB[c] = 0.f; }
    float ssA = 0.f, ssB = 0.f;
    float bdA = -3.4e38f, bdB = -3.4e38f;   // running MAX of dot (== min d2)
    int   bjA = 0,        bjB = 0;

    // double buffer: 4 codes + seed-quad per slot
    f32x8 A0 = cc[0], A1 = cc[1], A2 = cc[2], A3 = cc[3];
    f32x4 AS = cs4[0];
    f32x8 B0 = cc[4], B1 = cc[5], B2 = cc[6], B3 = cc[7];
    f32x4 BS = cs4[1];

    // one code x two positions; 4+4 split dot chains; strict > argmax(dot)
    // in increasing k order == np.argmin first-occurrence
#define BODY(CV, SV, JJ)                                                       \
    {                                                                          \
        const int jj = (JJ);                                                   \
        float sA = SV + hv2A, sB = SV + hv2B;                                  \
        float tA0 = __builtin_fmaf(CV[0], hvA[0], sA);                         \
        float tB0 = __builtin_fmaf(CV[0], hvB[0], sB);                         \
        tA0 = __builtin_fmaf(CV[1], hvA[1], tA0);                             \
        tB0 = __builtin_fmaf(CV[1], hvB[1], tB0);                             \
        tA0 = __builtin_fmaf(CV[2], hvA[2], tA0);                             \
        tB0 = __builtin_fmaf(CV[2], hvB[2], tB0);                             \
        tA0 = __builtin_fmaf(CV[3], hvA[3], tA0);                             \
        tB0 = __builtin_fmaf(CV[3], hvB[3], tB0);                             \
        float tA1 = CV[4] * hvA[4];                                            \
        float tB1 = CV[4] * hvB[4];                                            \
        tA1 = __builtin_fmaf(CV[5], hvA[5], tA1);                             \
        tB1 = __builtin_fmaf(CV[5], hvB[5], tB1);                             \
        tA1 = __builtin_fmaf(CV[6], hvA[6], tA1);                             \
        tB1 = __builtin_fmaf(CV[6], hvB[6], tB1);                             \
        tA1 = __builtin_fmaf(CV[7], hvA[7], tA1);                             \
        tB1 = __builtin_fmaf(CV[7], hvB[7], tB1);                             \
        float dA = tA0 + tA1;                                                  \
        float dB = tB0 + tB1;                                                  \
        float eA = EXP2NEG(__builtin_amdgcn_sqrtf(-dA));                       \
        float eB = EXP2NEG(__builtin_amdgcn_sqrtf(-dB));                       \
        ssA += eA; ssB += eB;                                                  \
        _Pragma("unroll")                                                      \
        for (int c = 0; c < CD; ++c) {                                         \
            accA[c] = __builtin_fmaf(CV[c], eA, accA[c]);                      \
            accB[c] = __builtin_fmaf(CV[c], eB, accB[c]);                      \
        }                                                                      \
        if (dA > bdA) bjA = jj;                                                \
        bdA = fmaxf(bdA, dA);                                                  \
        if (dB > bdB) bjB = jj;                                                \
        bdB = fmaxf(bdB, dB);                                                  \
    }

    for (int j = 0; j < KK; j += 8) {
        BODY(A0, AS[0], j)
        BODY(A1, AS[1], j + 1)
        BODY(A2, AS[2], j + 2)
        BODY(A3, AS[3], j + 3)
        {   // reload A <- codes j+8 (wrap at tail; wrapped values unused)
            const int jn = (j + 8) & (KK - 1);
            A0 = cc[jn]; A1 = cc[jn + 1]; A2 = cc[jn + 2]; A3 = cc[jn + 3];
            AS = cs4[jn >> 2];
        }
        BODY(B0, BS[0], j + 4)
        BODY(B1, BS[1], j + 5)
        BODY(B2, BS[2], j + 6)
        BODY(B3, BS[3], j + 7)
        {   // reload B <- codes j+12
            const int jm = (j + 12) & (KK - 1);
            B0 = cc[jm]; B1 = cc[jm + 1]; B2 = cc[jm + 2]; B3 = cc[jm + 3];
            BS = cs4[jm >> 2];
        }
    }
#undef BODY

    const float scA = INVFS / ssA;   // un-scale codes + softmax normalize
    const float scB = INVFS / ssB;

    const size_t obaseA = (size_t)pA * CCH + (size_t)(l4 * CD);
    const size_t obaseB = (size_t)pB * CCH + (size_t)(l4 * CD);
    *(f32x4*)&out[obaseA]     = (f32x4){accA[0]*scA, accA[1]*scA, accA[2]*scA, accA[3]*scA};
    *(f32x4*)&out[obaseA + 4] = (f32x4){accA[4]*scA, accA[5]*scA, accA[6]*scA, accA[7]*scA};
    *(f32x4*)&out[obaseB]     = (f32x4){accB[0]*scB, accB[1]*scB, accB[2]*scB, accB[3]*scB};
    *(f32x4*)&out[obaseB + 4] = (f32x4){accB[4]*scB, accB[5]*scB, accB[6]*scB, accB[7]*scB};

    // hard: gather un-scaled code from global (L2-hot 128 KB)
    float* outh = out + (size_t)NPOS * CCH;
    {
        const float* hp = codes + ((size_t)(l4 * KK + bjA)) * CD;
        *(f32x4*)&outh[obaseA]     = ((const f32x4*)hp)[0];
        *(f32x4*)&outh[obaseA + 4] = ((const f32x4*)hp)[1];
    }
    {
        const float* hp = codes + ((size_t)(l4 * KK + bjB)) * CD;
        *(f32x4*)&outh[obaseB]     = ((const f32x4*)hp)[0];
        *(f32x4*)&outh[obaseB + 4] = ((const f32x4*)hp)[1];
    }

    float* outi = out + (size_t)2 * NPOS * CCH;
    outi[(size_t)pA * LL + l4] = (float)bjA;
    outi[(size_t)pB * LL + l4] = (float)bjB;
}

extern "C" void kernel_launch(void* const* d_in, const int* in_sizes, int n_in,
                              void* d_out, int out_size, void* d_ws, size_t ws_size,
                              hipStream_t stream) {
    const float* z     = (const float*)d_in[0];
    const float* codes = (const float*)d_in[1];
    float* ws  = (float*)d_ws;
    float* out = (float*)d_out;
    prep_codes<<<dim3(16), dim3(256), 0, stream>>>(codes, ws);
    soft_hard_enc<<<dim3((NPOS / 512) * LL), dim3(256), 0, stream>>>(z, codes, ws, out);
}

// Round 7
// 141.379 us; speedup vs baseline: 1.3453x; 1.0280x over previous
//
#include <hip/hip_runtime.h>

// z(8,128,64,64) f32, codes(16,256,8) f32
// out: soft(8,64,64,128) | hard(8,64,64,128) | idx(8,64,64,16) as f32
#define NPOS 32768
#define CCH  128
#define LL   16
#define KK   256
#define CD   8

typedef float f32x4  __attribute__((ext_vector_type(4)));
typedef float f32x8  __attribute__((ext_vector_type(8)));
typedef short s16x8  __attribute__((ext_vector_type(8)));
typedef unsigned int u32x4 __attribute__((ext_vector_type(4)));

#if __has_builtin(__builtin_amdgcn_exp2f)
#define EXP2NEG(x) __builtin_amdgcn_exp2f(-(x))
#else
#define EXP2NEG(x) __expf(-0.6931471805599453f * (x))
#endif

// F = sqrt(2)*log2(e): dot' = -0.5|hv'|^2 -0.5|c'|^2 + hv'.c' = -(log2e*dist)^2
// => exp2(-sqrt(-dot')) == exp(-dist) exactly (softmin temperature 1.0)
#define FS 2.0402788939f

// ws (floats): [0,32768) scaled codes [16][256][8]
//              [32768,36864) seeds -0.5|c'|^2 [16][256]
//              [36864,69632) bf16 B-frags [16][8 chunks][64 lanes][8 bf16]
#define WS_SEED_OFF 32768
#define WS_BF_OFF   36864

__device__ __forceinline__ unsigned short bf16rne(float x) {
    unsigned u = __builtin_bit_cast(unsigned, x);
    u += 0x7fffu + ((u >> 16) & 1u);
    return (unsigned short)(u >> 16);
}

__global__ __launch_bounds__(256) void prep_codes(
    const float* __restrict__ codes, float* __restrict__ ws)
{
    const int t = (int)(blockIdx.x * 256 + threadIdx.x);   // 0..8191
    if (t < 4096) {                    // scaled codes + seeds (as R6)
        const int l = t >> 8, k = t & 255;
        const float* g = codes + ((size_t)(l * KK + k)) * CD;
        f32x4 q0 = FS * ((const f32x4*)g)[0];
        f32x4 q1 = FS * ((const f32x4*)g)[1];
        f32x4* d = (f32x4*)(ws + (size_t)l * 2048 + (size_t)k * CD);
        d[0] = q0;
        d[1] = q1;
        float c2 = q0[0]*q0[0] + q0[1]*q0[1] + q0[2]*q0[2] + q0[3]*q0[3]
                 + q1[0]*q1[0] + q1[1]*q1[1] + q1[2]*q1[2] + q1[3]*q1[3];
        ws[WS_SEED_OFF + l * KK + k] = -0.5f * c2;
    }
    // bf16 B-frag for mfma_f32_16x16x32_bf16:
    // B[k][col]: frag elem i of lane ln = B[8*(ln>>4)+i][ln&15]
    // chunk j covers codes 32j..32j+31; col<8 -> unscaled code channel, else 0
    const int l  = t >> 9;
    const int j  = (t >> 6) & 7;
    const int ln = t & 63;
    const int phi = ln >> 4, ch = ln & 15;
    unsigned short f[8];
#pragma unroll
    for (int i = 0; i < 8; ++i) {
        const int k = 32 * j + 8 * phi + i;
        f[i] = (ch < CD) ? bf16rne(codes[((size_t)(l * KK + k)) * CD + ch])
                         : (unsigned short)0;
    }
    u32x4 w4;
#pragma unroll
    for (int m = 0; m < 4; ++m)
        w4[m] = (unsigned)f[2 * m] | ((unsigned)f[2 * m + 1] << 16);
    ((u32x4*)(ws + WS_BF_OFF))[t] = w4;
}

// exact fp32 dot chain, bit-identical to R6's BODY
#define DOT8(CV, HV, SEED)                                   \
    ({  float _t0 = __builtin_fmaf(CV[0], HV[0], (SEED));    \
        _t0 = __builtin_fmaf(CV[1], HV[1], _t0);             \
        _t0 = __builtin_fmaf(CV[2], HV[2], _t0);             \
        _t0 = __builtin_fmaf(CV[3], HV[3], _t0);             \
        float _t1 = CV[4] * HV[4];                           \
        _t1 = __builtin_fmaf(CV[5], HV[5], _t1);             \
        _t1 = __builtin_fmaf(CV[6], HV[6], _t1);             \
        _t1 = __builtin_fmaf(CV[7], HV[7], _t1);             \
        _t0 + _t1; })

__global__ __launch_bounds__(256, 4) void soft_hard_enc(
    const float* __restrict__ z, const float* __restrict__ codes,
    const float* __restrict__ ws, float* __restrict__ out)
{
    const int tid = (int)threadIdx.x;
    const int bid = (int)blockIdx.x;
    // XCD-aware decomposition (R5/R6): latent is BLOCK-uniform -> SMEM code stream
    const int xcd   = bid & 7;
    const int m     = bid >> 3;
    const int l4    = m & 15;
    const int grp   = m >> 4;
    const int chunk = grp * 8 + xcd;
    const int posBase = chunk * 512;
    const int w    = tid >> 6;            // wave id
    const int lane = tid & 63;
    const int pA  = posBase + tid;        // 2 positions per thread
    const int pB  = pA + 256;
    const int b   = pA >> 12;
    const int whA = pA & 4095;

    // hv loads (coalesced per channel), scaled; -0.5*|hv'|^2   (identical to R6)
    const float* zp = z + (((size_t)(b * CCH + l4 * CD)) << 12) + whA;
    float hvA[CD], hvB[CD];
    float hv2A = 0.f, hv2B = 0.f;
#pragma unroll
    for (int c = 0; c < CD; ++c) {
        float va = FS * zp[((size_t)c) << 12];
        float vb = FS * zp[(((size_t)c) << 12) + 256];
        hvA[c] = va; hvB[c] = vb;
        hv2A = __builtin_fmaf(va, va, hv2A);
        hv2B = __builtin_fmaf(vb, vb, hv2B);
    }
    hv2A *= -0.5f;
    hv2B *= -0.5f;

    // block-uniform code streams -> SMEM (proven R6 path)
    const f32x8* cc  = (const f32x8*)(ws + (size_t)l4 * 2048);             // [256] codes
    const f32x8* cs8 = (const f32x8*)(ws + WS_SEED_OFF + (size_t)l4 * KK); // [32] seed octets

    // per-wave e-buffer: 128 rows (64 pA + 64 pB) x 32 codes bf16 = 8 KB
    __shared__ unsigned int ebuf[4 * 2048];
    unsigned int* eb = ebuf + w * 2048;
    const u32x4* bfp = ((const u32x4*)(ws + WS_BF_OFF)) + (size_t)l4 * 512 + lane;

    float ssA = 0.f, ssB = 0.f;
    float bdA = -3.4e38f, bdB = -3.4e38f;
    int   bjA = 0,        bjB = 0;
    f32x4 D[8];
#pragma unroll
    for (int t = 0; t < 8; ++t) D[t] = (f32x4){0.f, 0.f, 0.f, 0.f};

    const int swz = (lane >> 1) & 3;

    for (int j = 0; j < 8; ++j) {               // 8 chunks x 32 codes
        u32x4 bw = bfp[j * 64];                 // B-frag, issued early (VMEM)
#pragma unroll
        for (int h = 0; h < 2; ++h) {           // half-chunk: 16 codes
            unsigned uA[8], uB[8];
#pragma unroll
            for (int g = 0; g < 2; ++g) {       // 8 codes
                const int base = j * 32 + h * 16 + g * 8;
                f32x8 sd = cs8[base >> 3];
#pragma unroll
                for (int p = 0; p < 4; ++p) {   // code pair
                    const int k0 = base + 2 * p;
                    f32x8 Ce = cc[k0];
                    f32x8 Co = cc[k0 + 1];
                    const float se = sd[2 * p], so = sd[2 * p + 1];
                    float dA0 = DOT8(Ce, hvA, se + hv2A);
                    float dA1 = DOT8(Co, hvA, so + hv2A);
                    float dB0 = DOT8(Ce, hvB, se + hv2B);
                    float dB1 = DOT8(Co, hvB, so + hv2B);
                    float eA0 = EXP2NEG(__builtin_amdgcn_sqrtf(-dA0));
                    float eA1 = EXP2NEG(__builtin_amdgcn_sqrtf(-dA1));
                    float eB0 = EXP2NEG(__builtin_amdgcn_sqrtf(-dB0));
                    float eB1 = EXP2NEG(__builtin_amdgcn_sqrtf(-dB1));
                    ssA += eA0; ssA += eA1; ssB += eB0; ssB += eB1;
                    if (dA0 > bdA) bjA = k0;
                    bdA = fmaxf(bdA, dA0);
                    if (dA1 > bdA) bjA = k0 + 1;
                    bdA = fmaxf(bdA, dA1);
                    if (dB0 > bdB) bjB = k0;
                    bdB = fmaxf(bdB, dB0);
                    if (dB1 > bdB) bjB = k0 + 1;
                    bdB = fmaxf(bdB, dB1);
                    unsigned pa, pb;
                    asm("v_cvt_pk_bf16_f32 %0, %1, %2" : "=v"(pa) : "v"(eA0), "v"(eA1));
                    asm("v_cvt_pk_bf16_f32 %0, %1, %2" : "=v"(pb) : "v"(eB0), "v"(eB1));
                    uA[g * 4 + p] = pa;
                    uB[g * 4 + p] = pb;
                }
            }
            // swizzled e-writes: row r, colgroup c -> u32 idx r*16 + 4*(c^swz)
            *(u32x4*)&eb[lane * 16        + 4 * ((2 * h)     ^ swz)] = *(const u32x4*)&uA[0];
            *(u32x4*)&eb[lane * 16        + 4 * ((2 * h + 1) ^ swz)] = *(const u32x4*)&uA[4];
            *(u32x4*)&eb[(64 + lane) * 16 + 4 * ((2 * h)     ^ swz)] = *(const u32x4*)&uB[0];
            *(u32x4*)&eb[(64 + lane) * 16 + 4 * ((2 * h + 1) ^ swz)] = *(const u32x4*)&uB[4];
        }
        // MFMA phase: D[t] += P_tile(16pos x 32codes) @ codesT(32 x 8ch)
        s16x8 B = __builtin_bit_cast(s16x8, bw);
#pragma unroll
        for (int t = 0; t < 8; ++t) {
            const int row = ((t & 3) << 4) + (lane & 15) + ((t >> 2) << 6);
            const int cg  = (lane >> 4) ^ ((row >> 1) & 3);
            s16x8 A = *(const s16x8*)&eb[row * 16 + 4 * cg];
            D[t] = __builtin_amdgcn_mfma_f32_16x16x32_bf16(A, B, D[t], 0, 0, 0);
        }
    }

    // soft epilogue: D row=(lane>>4)*4+q, col=lane&15 (channel); scale by 1/ssum(pos)
    const float rA = 1.0f / ssA;
    const float rB = 1.0f / ssB;
    const int ch = lane & 15;
    const int rowgrp = (lane >> 4) << 2;
#pragma unroll
    for (int t = 0; t < 8; ++t) {
        const int tb  = (t & 3) << 4;
        const int off = (t >> 2) ? 256 : 0;
#pragma unroll
        for (int q = 0; q < 4; ++q) {
            const int r = tb + rowgrp + q;                 // owner lane 0..63
            const float rinv = __shfl((t >= 4) ? rB : rA, r, 64);
            if (ch < CD) {
                const int pos = posBase + w * 64 + off + r;
                out[(size_t)pos * CCH + l4 * CD + ch] = D[t][q] * rinv;
            }
        }
    }

    // hard + idx: unchanged (exact fp32 argmin path)
    const size_t obaseA = (size_t)pA * CCH + (size_t)(l4 * CD);
    const size_t obaseB = (size_t)pB * CCH + (size_t)(l4 * CD);
    float* outh = out + (size_t)NPOS * CCH;
    {
        const float* hp = codes + ((size_t)(l4 * KK + bjA)) * CD;
        *(f32x4*)&outh[obaseA]     = ((const f32x4*)hp)[0];
        *(f32x4*)&outh[obaseA + 4] = ((const f32x4*)hp)[1];
    }
    {
        const float* hp = codes + ((size_t)(l4 * KK + bjB)) * CD;
        *(f32x4*)&outh[obaseB]     = ((const f32x4*)hp)[0];
        *(f32x4*)&outh[obaseB + 4] = ((const f32x4*)hp)[1];
    }
    float* outi = out + (size_t)2 * NPOS * CCH;
    outi[(size_t)pA * LL + l4] = (float)bjA;
    outi[(size_t)pB * LL + l4] = (float)bjB;
}

extern "C" void kernel_launch(void* const* d_in, const int* in_sizes, int n_in,
                              void* d_out, int out_size, void* d_ws, size_t ws_size,
                              hipStream_t stream) {
    const float* z     = (const float*)d_in[0];
    const float* codes = (const float*)d_in[1];
    float* ws  = (float*)d_ws;
    float* out = (float*)d_out;
    prep_codes<<<dim3(32), dim3(256), 0, stream>>>(codes, ws);
    soft_hard_enc<<<dim3((NPOS / 512) * LL), dim3(256), 0, stream>>>(z, codes, ws, out);
}

// Round 8
// 110.988 us; speedup vs baseline: 1.7136x; 1.2738x over previous
//
#include <hip/hip_runtime.h>

// z(8,128,64,64) f32, codes(16,256,8) f32
// out: soft(8,64,64,128) | hard(8,64,64,128) | idx(8,64,64,16) as f32
#define NPOS 32768
#define CCH  128
#define LL   16
#define KK   256
#define CD   8

typedef float f32x4 __attribute__((ext_vector_type(4)));
typedef _Float16 f16x8 __attribute__((ext_vector_type(8)));
typedef _Float16 f16x2 __attribute__((ext_vector_type(2)));
typedef unsigned int u32x2 __attribute__((ext_vector_type(2)));
typedef unsigned int u32x4 __attribute__((ext_vector_type(4)));

// F = sqrt(2)*log2(e): D = hv'.c' -0.5|c'|^2 -0.5|hv'|^2 = -(log2e*dist)^2
// => exp2(-sqrt(-D)) == exp(-dist)  (softmin temperature exactly 1.0)
#define FS 2.0402788939f

// ws (u32x4 units): [0, 16384)          d2 A-frags [16 lat][16 tiles][64 lanes]
//                   [16384, 24576)      PV A-frags [16 lat][8 chunks][64 lanes]
#define WS_PVA4 16384

__device__ __forceinline__ unsigned pk16(_Float16 a, _Float16 b) {
    f16x2 p = {a, b};
    return __builtin_bit_cast(unsigned, p);
}

__global__ __launch_bounds__(256) void prep_codes(
    const float* __restrict__ codes, float* __restrict__ ws)
{
    const int t = (int)(blockIdx.x * 256 + threadIdx.x);   // 0..24575
    u32x4* w4 = (u32x4*)ws;
    if (t < 16384) {
        // d2 A-frag: A[row=code-in-tile][k]; lane g covers k-slots 8g..8g+7
        // slots: [0:8)=c'_hi  [8:16)=c'_lo  [16:24)=c'_hi  [24..27]=s_hi,s_lo,1,1
        const int l = t >> 10, tile = (t >> 6) & 15, ln = t & 63;
        const int g = ln >> 4, row = ln & 15;
        const float* cp = codes + ((size_t)(l * KK + 16 * tile + row)) * CD;
        float c[8]; float s2 = 0.f;
#pragma unroll
        for (int i = 0; i < 8; ++i) { c[i] = FS * cp[i]; s2 = __builtin_fmaf(c[i], c[i], s2); }
        const float seed = -0.5f * s2;
        _Float16 h[8];
        if (g == 1) {
#pragma unroll
            for (int i = 0; i < 8; ++i) {
                _Float16 hi = (_Float16)c[i];
                h[i] = (_Float16)(c[i] - (float)hi);
            }
        } else if (g == 3) {
            _Float16 sh = (_Float16)seed;
            _Float16 sl = (_Float16)(seed - (float)sh);
            h[0] = sh; h[1] = sl; h[2] = (_Float16)1.0f; h[3] = (_Float16)1.0f;
            h[4] = h[5] = h[6] = h[7] = (_Float16)0.0f;
        } else {  // g==0 or g==2: c'_hi
#pragma unroll
            for (int i = 0; i < 8; ++i) h[i] = (_Float16)c[i];
        }
        u32x4 o = {pk16(h[0],h[1]), pk16(h[2],h[3]), pk16(h[4],h[5]), pk16(h[6],h[7])};
        w4[(size_t)(l * 16 + tile) * 64 + ln] = o;
    } else {
        // PV A-frag: A[row][k=code-in-chunk]; rows 0-7 = channel (unscaled code),
        // row 8 = ones (ssum), rows 9-15 = 0. lane g covers codes 8g..8g+7.
        const int u = t - 16384;
        const int l = u >> 9, ch = (u >> 6) & 7, ln = u & 63;
        const int g = ln >> 4, row = ln & 15;
        _Float16 h[8];
#pragma unroll
        for (int i = 0; i < 8; ++i) {
            const int code = 32 * ch + 8 * g + i;
            h[i] = (row < 8) ? (_Float16)codes[((size_t)(l * KK + code)) * CD + row]
                 : (row == 8) ? (_Float16)1.0f : (_Float16)0.0f;
        }
        u32x4 o = {pk16(h[0],h[1]), pk16(h[2],h[3]), pk16(h[4],h[5]), pk16(h[6],h[7])};
        w4[WS_PVA4 + (size_t)(l * 8 + ch) * 64 + ln] = o;
    }
}

__global__ __launch_bounds__(256, 4) void soft_hard_enc(
    const float* __restrict__ z, const float* __restrict__ codes,
    const float* __restrict__ ws, float* __restrict__ out)
{
    __shared__ unsigned int ebuf[4][64][16];   // 16 KB: per-wave e-tiles (f16 pairs)

    const int tid = (int)threadIdx.x;
    const int bid = (int)blockIdx.x;
    // XCD grouping (R6-proven): same-chunk latent-blocks share bid%8 -> write merge
    const int l4    = (bid >> 3) & 15;
    const int chunk = ((bid >> 7) << 3) | (bid & 7);
    const int w  = tid >> 6, ln = tid & 63;
    const int g  = ln >> 4,  cl = ln & 15;
    const int posW = chunk * 256 + w * 64;
    const int pos  = posW + ln;
    const int b = pos >> 12, wh = pos & 4095;

    // hv' (F-scaled fp32) + hv2 = -0.5|hv'|^2
    const float* zp = z + (((size_t)(b * CCH + l4 * CD)) << 12) + wh;
    float hvF[8]; float hv2 = 0.f;
#pragma unroll
    for (int c = 0; c < 8; ++c) {
        float v = FS * zp[((size_t)c) << 12];
        hvF[c] = v;
        hv2 = __builtin_fmaf(v, v, hv2);
    }
    hv2 *= -0.5f;

    // f16 hi/lo split of hv' (packed pairs) + hv2 split
    unsigned hh[4], hl[4], hv2p;
#pragma unroll
    for (int j = 0; j < 4; ++j) {
        _Float16 a0 = (_Float16)hvF[2*j], a1 = (_Float16)hvF[2*j+1];
        _Float16 b0 = (_Float16)(hvF[2*j]   - (float)a0);
        _Float16 b1 = (_Float16)(hvF[2*j+1] - (float)a1);
        hh[j] = pk16(a0, a1);
        hl[j] = pk16(b0, b1);
    }
    {
        _Float16 s0 = (_Float16)hv2;
        _Float16 s1 = (_Float16)(hv2 - (float)s0);
        hv2p = pk16(s0, s1);
    }

    // d2 B-frags (4 pos-frags). B[k][col=pos]: lane g covers k-slots 8g..8g+7:
    // g0,g1 = h_hi ; g2 = h_lo ; g3 = [1,1,hv2_hi,hv2_lo,0,0,0,0]
    const unsigned ONE2 = 0x3C003C00u;
    u32x4 Bv[4];
#pragma unroll
    for (int f = 0; f < 4; ++f) {
        const int sp = 16 * f + cl;
        unsigned bh0=__shfl(hh[0],sp,64), bh1=__shfl(hh[1],sp,64),
                 bh2=__shfl(hh[2],sp,64), bh3=__shfl(hh[3],sp,64);
        unsigned bl0=__shfl(hl[0],sp,64), bl1=__shfl(hl[1],sp,64),
                 bl2=__shfl(hl[2],sp,64), bl3=__shfl(hl[3],sp,64);
        unsigned bp = __shfl(hv2p, sp, 64);
        u32x4 v;
        if (g <= 1)      v = (u32x4){bh0, bh1, bh2, bh3};
        else if (g == 2) v = (u32x4){bl0, bl1, bl2, bl3};
        else             v = (u32x4){ONE2, bp, 0u, 0u};
        Bv[f] = v;
    }

    const u32x4* a4  = (const u32x4*)ws + (size_t)l4 * 1024 + ln;          // d2 A
    const u32x4* apv = (const u32x4*)ws + WS_PVA4 + (size_t)l4 * 512 + ln; // PV A

    f32x4 ACC[4];
#pragma unroll
    for (int f = 0; f < 4; ++f) ACC[f] = (f32x4){0.f, 0.f, 0.f, 0.f};
    unsigned K1a[4] = {~0u, ~0u, ~0u, ~0u};
    unsigned K2a[4] = {~0u, ~0u, ~0u, ~0u};

    int rowf[4], swzf[4];
#pragma unroll
    for (int f = 0; f < 4; ++f) { rowf[f] = 16 * f + cl; swzf[f] = (rowf[f] >> 1) & 3; }

    unsigned int (*eb)[16] = ebuf[w];
    u32x4 Abuf = a4[0];
    u32x4 ApvB = apv[0];
    const int vg4 = g << 2;

#pragma unroll
    for (int t = 0; t < 16; ++t) {
        u32x4 Anext = a4[(size_t)(((t + 1) & 15)) * 64];
        f16x8 Af = __builtin_bit_cast(f16x8, Abuf);

        f32x4 D[4];
#pragma unroll
        for (int f = 0; f < 4; ++f)
            D[f] = __builtin_amdgcn_mfma_f32_16x16x32_f16(
                Af, __builtin_bit_cast(f16x8, Bv[f]),
                (f32x4){0.f, 0.f, 0.f, 0.f}, 0, 0, 0);

#pragma unroll
        for (int f = 0; f < 4; ++f) {
            const unsigned idxor = (unsigned)(16 * t) | (unsigned)vg4;
            float e[4];
#pragma unroll
            for (int q = 0; q < 4; ++q) {
                float d = D[f][q];
                float s = __builtin_amdgcn_sqrtf(__builtin_fabsf(d));  // NaN-safe
                e[q] = __builtin_amdgcn_exp2f(-s);                     // exp(-dist)
                unsigned u = __builtin_bit_cast(unsigned, d);
                unsigned key = (u & 0xFFFFFF00u) | (idxor + (unsigned)q);
                unsigned mx = (key > K1a[f]) ? key : K1a[f];
                K2a[f] = (mx < K2a[f]) ? mx : K2a[f];
                K1a[f] = (key < K1a[f]) ? key : K1a[f];
            }
            unsigned E0 = __builtin_bit_cast(unsigned, __builtin_amdgcn_cvt_pkrtz(e[0], e[1]));
            unsigned E1 = __builtin_bit_cast(unsigned, __builtin_amdgcn_cvt_pkrtz(e[2], e[3]));
            const int cgl = ((t & 1) << 1) | (g >> 1);
            const int cgs = cgl ^ swzf[f];
            *(u32x2*)&eb[rowf[f]][cgs * 4 + ((g & 1) << 1)] = (u32x2){E0, E1};
        }

        if (t & 1) {   // chunk complete: PV accumulate (same-wave LDS, in-order, no barrier)
            const int c = t >> 1;
            u32x4 ApvN = apv[(size_t)(((c + 1) & 7)) * 64];
            f16x8 Ap = __builtin_bit_cast(f16x8, ApvB);
#pragma unroll
            for (int f = 0; f < 4; ++f) {
                u32x4 bw = *(const u32x4*)&eb[rowf[f]][(g ^ swzf[f]) * 4];
                ACC[f] = __builtin_amdgcn_mfma_f32_16x16x32_f16(
                    Ap, __builtin_bit_cast(f16x8, bw), ACC[f], 0, 0, 0);
            }
            ApvB = ApvN;
        }
        Abuf = Anext;
    }

    // ---- argmin finalize: per-frag cross-g min2 reduce, then lane picks f = g
#pragma unroll
    for (int f = 0; f < 4; ++f) {
#pragma unroll
        for (int m = 0; m < 2; ++m) {
            const int mask = m ? 32 : 16;
            unsigned o1 = __shfl_xor(K1a[f], mask, 64);
            unsigned o2 = __shfl_xor(K2a[f], mask, 64);
            unsigned mx = (K1a[f] > o1) ? K1a[f] : o1;
            unsigned mn2 = (K2a[f] < o2) ? K2a[f] : o2;
            K2a[f] = (mx < mn2) ? mx : mn2;
            K1a[f] = (o1 < K1a[f]) ? o1 : K1a[f];
        }
    }
    unsigned K1 = (g == 0) ? K1a[0] : (g == 1) ? K1a[1] : (g == 2) ? K1a[2] : K1a[3];
    unsigned K2 = (g == 0) ? K2a[0] : (g == 1) ? K2a[1] : (g == 2) ? K2a[2] : K2a[3];

    float m1f = __builtin_bit_cast(float, K1 & 0xFFFFFF00u);
    float m2f = __builtin_bit_cast(float, K2 & 0xFFFFFF00u);
    int i1 = (int)(K1 & 255u), i2 = (int)(K2 & 255u);
    int bk = i1;
    const float tau = __builtin_fmaf(__builtin_fabsf(m1f), 6.1e-5f, 1e-3f);
    if (m1f - m2f < tau) {   // exact fp32 top-2 recheck (rare)
        float dv0, dv1;
        {
            const float* cp = codes + ((size_t)(l4 * KK + i1)) * CD;
            float s = 0.f, cc[8];
#pragma unroll
            for (int c = 0; c < 8; ++c) { cc[c] = FS * cp[c]; s = __builtin_fmaf(cc[c], cc[c], s); }
            float d = __builtin_fmaf(-0.5f, s, hv2);
#pragma unroll
            for (int c = 0; c < 8; ++c) d = __builtin_fmaf(cc[c], hvF[c], d);
            dv0 = d;
        }
        {
            const float* cp = codes + ((size_t)(l4 * KK + i2)) * CD;
            float s = 0.f, cc[8];
#pragma unroll
            for (int c = 0; c < 8; ++c) { cc[c] = FS * cp[c]; s = __builtin_fmaf(cc[c], cc[c], s); }
            float d = __builtin_fmaf(-0.5f, s, hv2);
#pragma unroll
            for (int c = 0; c < 8; ++c) d = __builtin_fmaf(cc[c], hvF[c], d);
            dv1 = d;
        }
        bk = (dv1 > dv0 || (dv1 == dv0 && i2 < i1)) ? i2 : i1;
    }

    // ---- soft epilogue: D[row=ch][col=pos], row 8 = ssum; >=16B stores
#pragma unroll
    for (int f = 0; f < 4; ++f) {
        float ssv = __shfl(ACC[f][0], cl + 32, 64);   // row 8 (g=2, q=0)
        float sc = __builtin_amdgcn_rcpf(ssv);
        if (g < 2) {
            const int p = posW + 16 * f + cl;
            f32x4 v = {ACC[f][0]*sc, ACC[f][1]*sc, ACC[f][2]*sc, ACC[f][3]*sc};
            *(f32x4*)&out[(size_t)p * CCH + l4 * CD + 4 * g] = v;
        }
    }

    // ---- hard + idx (lane owns pos = posW + ln)
    float* outh = out + (size_t)NPOS * CCH;
    float* outi = out + (size_t)2 * NPOS * CCH;
    const float* hp = codes + ((size_t)(l4 * KK + bk)) * CD;
    f32x4 h0 = ((const f32x4*)hp)[0];
    f32x4 h1 = ((const f32x4*)hp)[1];
    *(f32x4*)&outh[(size_t)pos * CCH + l4 * CD]     = h0;
    *(f32x4*)&outh[(size_t)pos * CCH + l4 * CD + 4] = h1;
    outi[(size_t)pos * LL + l4] = (float)bk;
}

extern "C" void kernel_launch(void* const* d_in, const int* in_sizes, int n_in,
                              void* d_out, int out_size, void* d_ws, size_t ws_size,
                              hipStream_t stream) {
    const float* z     = (const float*)d_in[0];
    const float* codes = (const float*)d_in[1];
    float* ws  = (float*)d_ws;
    float* out = (float*)d_out;
    prep_codes<<<dim3(96), dim3(256), 0, stream>>>(codes, ws);
    soft_hard_enc<<<dim3(2048), dim3(256), 0, stream>>>(z, codes, ws, out);
}